// Round 7
// baseline (742.773 us; speedup 1.0000x reference)
//
#include <hip/hip_runtime.h>
#include <hip/hip_bf16.h>

// ---------------- constants ----------------
#define L1X   1500   // raw sequence length
#define L1P   751    // pool1 length (t in [0,750])
#define C1    64
#define L2P   377    // pool2 length
#define C2    128
#define L3P   191    // pool3 length
#define C3    128
#define FEATK 24448  // L3P*C3 (stored [i][c] -> k = i*128 + c)
#define D2    256
#define HIDN  128
#define KSTEPS 764   // FEATK / 32

typedef __attribute__((ext_vector_type(8))) short bf16x8;
typedef __attribute__((ext_vector_type(4))) float f32x4;

__device__ __forceinline__ short f2bf(float x) {
    union { float f; unsigned u; } v; v.f = x;
    unsigned r = (v.u + 0x7FFFu + ((v.u >> 16) & 1u)) >> 16;
    return (short)r;
}
__device__ __forceinline__ float bf2f(short s) {
    union { float f; unsigned u; } v; v.u = ((unsigned)(unsigned short)s) << 16;
    return v.f;
}

// =====================================================================
// Conv weight prep: w[OC=128][IC][3] fp32 -> Wt[tap][kb][sub][c][8] bf16 hi/lo
// =====================================================================
template<int IC, int KB>
__global__ __launch_bounds__(256)
void k_wprep(const float* __restrict__ w, short* __restrict__ WtHi,
             short* __restrict__ WtLo)
{
    int idx = blockIdx.x * 256 + threadIdx.x;
    if (idx >= 3 * KB * 4 * 128 * 8) return;
    int i    = idx & 7;
    int rest = idx >> 3;
    int c    = rest & 127; rest >>= 7;
    int sub  = rest & 3;   rest >>= 2;
    int kb   = rest % KB;
    int tap  = rest / KB;
    int ic   = kb * 32 + sub * 8 + i;
    float x  = w[(c * IC + ic) * 3 + tap];
    short h  = f2bf(x);
    WtHi[idx] = h;
    WtLo[idx] = f2bf(x - bf2f(h));
}

// =====================================================================
// map2 weight prep: W[f=c*191+ip][n] fp32 -> Wm[ks][sub][n][i] bf16 hi/lo
// (k = ip*128 + c = ks*32 + sub*8 + i). grid 764*4, block 256 (thread=n)
// =====================================================================
__global__ __launch_bounds__(256)
void k_wmprep(const float* __restrict__ W, short* __restrict__ Wmhi,
              short* __restrict__ Wmlo)
{
    const int ks  = blockIdx.x >> 2;
    const int sub = blockIdx.x & 3;
    const int n   = threadIdx.x;
    const int kbase = ks * 32 + sub * 8;
    bf16x8 vh, vl;
    #pragma unroll
    for (int i = 0; i < 8; ++i) {
        int k = kbase + i;
        int c = k & 127, ip = k >> 7;
        float x = W[(size_t)(c * 191 + ip) * D2 + n];
        short h = f2bf(x);
        vh[i] = h;
        vl[i] = f2bf(x - bf2f(h));
    }
    size_t off = ((size_t)(ks * 4 + sub) * 256 + n) * 8;
    *(bf16x8*)(Wmhi + off) = vh;
    *(bf16x8*)(Wmlo + off) = vl;
}

// =====================================================================
// zero-init kernel (accum buffer)
// =====================================================================
__global__ __launch_bounds__(256)
void k_zero(float* __restrict__ p, int n)
{
    int i = blockIdx.x * 256 + threadIdx.x;
    if (i < n) p[i] = 0.f;
}

// =====================================================================
// Shared MFMA conv core. HL=false: fp32 [i][c] out. HL=true: bf16 hi/lo planes.
// =====================================================================
template<int IC, int KB, int CONVLEN, int POOLLEN, bool HL>
__device__ __forceinline__
void conv_mfma_core(const short* __restrict__ WtHi, const short* __restrict__ WtLo,
                    const short* lhi, const short* llo,
                    const float* sc, const float* bc,
                    float* __restrict__ outp, short* __restrict__ ohi,
                    short* __restrict__ olo, int P0)
{
    const int lane = threadIdx.x & 63;
    const int wave = threadIdx.x >> 6;
    const int l15  = lane & 15;
    const int sub  = lane >> 4;

    f32x4 acc[2][8];
    #pragma unroll
    for (int mf = 0; mf < 2; ++mf)
        #pragma unroll
        for (int nf = 0; nf < 8; ++nf)
            acc[mf][nf] = (f32x4){0.f, 0.f, 0.f, 0.f};

    #pragma unroll
    for (int tap = 0; tap < 3; ++tap) {
        #pragma unroll
        for (int kb = 0; kb < KB; ++kb) {
            bf16x8 ah[2], al[2];
            #pragma unroll
            for (int mf = 0; mf < 2; ++mf) {
                int r = wave * 32 + mf * 16 + l15 + tap;
                int chunk = (kb * 4 + sub) ^ (r & 7);
                int off = r * IC + chunk * 8;
                ah[mf] = *(const bf16x8*)(lhi + off);
                al[mf] = *(const bf16x8*)(llo + off);
            }
            const short* wbh = WtHi + (size_t)(((tap * KB + kb) * 4 + sub) * 128) * 8;
            const short* wbl = WtLo + (size_t)(((tap * KB + kb) * 4 + sub) * 128) * 8;
            #pragma unroll
            for (int nf = 0; nf < 8; ++nf) {
                bf16x8 bh = *(const bf16x8*)(wbh + (nf * 16 + l15) * 8);
                bf16x8 bl = *(const bf16x8*)(wbl + (nf * 16 + l15) * 8);
                #pragma unroll
                for (int mf = 0; mf < 2; ++mf) {
                    acc[mf][nf] = __builtin_amdgcn_mfma_f32_16x16x32_bf16(ah[mf], bh, acc[mf][nf], 0, 0, 0);
                    acc[mf][nf] = __builtin_amdgcn_mfma_f32_16x16x32_bf16(ah[mf], bl, acc[mf][nf], 0, 0, 0);
                    acc[mf][nf] = __builtin_amdgcn_mfma_f32_16x16x32_bf16(al[mf], bh, acc[mf][nf], 0, 0, 0);
                }
            }
        }
    }

    #pragma unroll
    for (int mf = 0; mf < 2; ++mf) {
        int mbase = wave * 32 + mf * 16 + sub * 4;
        #pragma unroll
        for (int nf = 0; nf < 8; ++nf) {
            int c = nf * 16 + l15;
            float s = sc[c], bb = bc[c];
            float v[4];
            #pragma unroll
            for (int rg = 0; rg < 4; ++rg) {
                int p = P0 + mbase + rg;
                float x = fmaxf(acc[mf][nf][rg] * s + bb, 0.f);
                v[rg] = (p >= 0 && p < CONVLEN) ? x : 0.f;
            }
            int i0 = (P0 + mbase + 1) >> 1;    // pooled index (P0 odd)
            float u0 = fmaxf(v[0], v[1]);
            float u1 = fmaxf(v[2], v[3]);
            if constexpr (HL) {
                if (i0 < POOLLEN) {
                    short h = f2bf(u0);
                    ohi[(size_t)i0 * 128 + c] = h;
                    olo[(size_t)i0 * 128 + c] = f2bf(u0 - bf2f(h));
                }
                if (i0 + 1 < POOLLEN) {
                    short h = f2bf(u1);
                    ohi[(size_t)(i0 + 1) * 128 + c] = h;
                    olo[(size_t)(i0 + 1) * 128 + c] = f2bf(u1 - bf2f(h));
                }
            } else {
                if (i0 < POOLLEN)     outp[(size_t)i0 * 128 + c] = u0;
                if (i0 + 1 < POOLLEN) outp[(size_t)(i0 + 1) * 128 + c] = u1;
            }
        }
    }
}

// =====================================================================
// conv2 (fused conv1+bn1+relu+pool1 recompute prologue) -> MFMA
// =====================================================================
__global__ __launch_bounds__(256)
void k_conv2_mfma(const float* __restrict__ X, const float* __restrict__ w1,
                  const float* __restrict__ bn1,
                  const short* __restrict__ Wt2hi, const short* __restrict__ Wt2lo,
                  const float* __restrict__ bn2, float* __restrict__ pool2t,
                  int b_off)
{
    const int blk = blockIdx.x;
    const int bl  = blk / 6, t = blk % 6;
    const int b   = b_off + bl;
    const int P0  = 128 * t - 1;
    const int T0  = 128 * t - 3;
    const int X0  = 256 * t - 8;

    __shared__ __align__(16) float xw[264];
    __shared__ __align__(16) short t1h[130 * 64];
    __shared__ __align__(16) short t1l[130 * 64];
    __shared__ float sb1s[64], sb1b[64], sc2[128], bc2[128];

    const int tid = threadIdx.x;
    for (int g = tid; g < 262; g += 256) {
        int xi = X0 + g;
        xw[g] = (xi >= 0 && xi < L1X) ? X[(size_t)b * L1X + xi] : 0.f;
    }
    if (tid < 64) {
        float s = bn1[tid] * rsqrtf(bn1[192 + tid] + 1e-5f);
        sb1s[tid] = s;
        sb1b[tid] = bn1[64 + tid] - bn1[128 + tid] * s;
    }
    if (tid < 128) {
        float s = bn2[tid] * rsqrtf(bn2[384 + tid] + 1e-5f);
        sc2[tid] = s;
        bc2[tid] = bn2[128 + tid] - bn2[256 + tid] * s;
    }
    __syncthreads();

    for (int idx = tid; idx < 130 * 64; idx += 256) {
        int r = idx >> 6, c = idx & 63;
        int tt = T0 + r;
        float val = 0.f;
        if (tt >= 0 && tt <= 750) {
            float wk0 = w1[c * 3], wk1 = w1[c * 3 + 1], wk2 = w1[c * 3 + 2];
            float s = sb1s[c], bias = sb1b[c];
            float v0 = 0.f, v1 = 0.f;
            int li = 2 * r;
            if (tt >= 1)
                v0 = fmaxf((wk0 * xw[li] + wk1 * xw[li + 1] + wk2 * xw[li + 2]) * s + bias, 0.f);
            if (tt <= 749)
                v1 = fmaxf((wk0 * xw[li + 1] + wk1 * xw[li + 2] + wk2 * xw[li + 3]) * s + bias, 0.f);
            val = fmaxf(v0, v1);
        }
        short h = f2bf(val);
        int chunk = (c >> 3) ^ (r & 7);
        int off = r * 64 + chunk * 8 + (c & 7);
        t1h[off] = h;
        t1l[off] = f2bf(val - bf2f(h));
    }
    __syncthreads();

    conv_mfma_core<64, 2, 753, 377, false>(Wt2hi, Wt2lo, t1h, t1l, sc2, bc2,
                                           pool2t + (size_t)bl * L2P * 128,
                                           nullptr, nullptr, P0);
}

// =====================================================================
// conv3 MFMA -> pool3 bf16 hi/lo planes [row][i*128+c]
// =====================================================================
__global__ __launch_bounds__(256)
void k_conv3_mfma(const float* __restrict__ pool2t,
                  const short* __restrict__ Wt3hi, const short* __restrict__ Wt3lo,
                  const float* __restrict__ bn3, short* __restrict__ p3hi,
                  short* __restrict__ p3lo, int b_off)
{
    const int blk = blockIdx.x;
    const int bl  = blk / 3, t = blk % 3;
    const int b   = b_off + bl;
    const int P0  = 128 * t - 1;
    const int I0  = 128 * t - 4;

    __shared__ __align__(16) short t2h[130 * 128];
    __shared__ __align__(16) short t2l[130 * 128];
    __shared__ float sc3[128], bc3[128];

    const int tid = threadIdx.x;
    if (tid < 128) {
        float s = bn3[tid] * rsqrtf(bn3[384 + tid] + 1e-5f);
        sc3[tid] = s;
        bc3[tid] = bn3[128 + tid] - bn3[256 + tid] * s;
    }

    const float* src = pool2t + (size_t)bl * L2P * 128;
    for (int idx = tid; idx < 130 * 32; idx += 256) {
        int r = idx >> 5, q = idx & 31;
        int pr = I0 + r;
        float4 v = make_float4(0.f, 0.f, 0.f, 0.f);
        if (pr >= 0 && pr < L2P) v = *(const float4*)(src + (size_t)pr * 128 + q * 4);
        int chunk = (q >> 1) ^ (r & 7);
        int off = r * 128 + chunk * 8 + (q & 1) * 4;
        *(short4*)(t2h + off) = make_short4(f2bf(v.x), f2bf(v.y), f2bf(v.z), f2bf(v.w));
        short l0 = f2bf(v.x - bf2f(f2bf(v.x)));
        short l1 = f2bf(v.y - bf2f(f2bf(v.y)));
        short l2 = f2bf(v.z - bf2f(f2bf(v.z)));
        short l3 = f2bf(v.w - bf2f(f2bf(v.w)));
        *(short4*)(t2l + off) = make_short4(l0, l1, l2, l3);
    }
    __syncthreads();

    conv_mfma_core<128, 4, 381, 191, true>(Wt3hi, Wt3lo, t2h, t2l, sc3, bc3,
                                           nullptr,
                                           p3hi + (size_t)b * FEATK,
                                           p3lo + (size_t)b * FEATK, P0);
}

// =====================================================================
// map2 MFMA GEMM: accum += A[768,24448] @ W[24448,256], split-bf16 3-pass.
// grid 384: kt = bid&31 (same kt -> same XCD for W L2 reuse), mt = bid>>5.
// Block: 64 M x 256 N, 24 k-steps (last block 20). A double-buffered in
// LDS, stride 40 shorts (2-way banks, free). atomicAdd into accum.
// =====================================================================
__global__ __launch_bounds__(256)
void k_map2_mfma(const short* __restrict__ Ahi, const short* __restrict__ Alo,
                 const short* __restrict__ Wmhi, const short* __restrict__ Wmlo,
                 float* __restrict__ accum)
{
    const int kt   = blockIdx.x & 31;
    const int mt   = blockIdx.x >> 5;
    const int tid  = threadIdx.x;
    const int lane = tid & 63, wave = tid >> 6;
    const int l15  = lane & 15, sub = lane >> 4;
    const int wm   = wave >> 1, wn = wave & 1;
    const int m0   = mt * 64;

    const int s0 = kt * 24;
    const int s1 = (s0 + 24 < KSTEPS) ? s0 + 24 : KSTEPS;

    __shared__ __align__(16) short Ah[2][64 * 40];
    __shared__ __align__(16) short Al[2][64 * 40];

    const int r  = tid >> 2;
    const int kb = tid & 3;
    const size_t abase = (size_t)(m0 + r) * FEATK + kb * 8;
    const int    lbase = r * 40 + kb * 8;

    f32x4 acc[2][8];
    #pragma unroll
    for (int mf = 0; mf < 2; ++mf)
        #pragma unroll
        for (int nf = 0; nf < 8; ++nf)
            acc[mf][nf] = (f32x4){0.f, 0.f, 0.f, 0.f};

    *(bf16x8*)&Ah[0][lbase] = *(const bf16x8*)(Ahi + abase + (size_t)s0 * 32);
    *(bf16x8*)&Al[0][lbase] = *(const bf16x8*)(Alo + abase + (size_t)s0 * 32);

    int cur = 0;
    for (int s = s0; s < s1; ++s) {
        __syncthreads();
        if (s + 1 < s1) {
            *(bf16x8*)&Ah[cur ^ 1][lbase] = *(const bf16x8*)(Ahi + abase + (size_t)(s + 1) * 32);
            *(bf16x8*)&Al[cur ^ 1][lbase] = *(const bf16x8*)(Alo + abase + (size_t)(s + 1) * 32);
        }
        bf16x8 ah[2], al[2];
        #pragma unroll
        for (int mf = 0; mf < 2; ++mf) {
            int off = (wm * 32 + mf * 16 + l15) * 40 + sub * 8;
            ah[mf] = *(const bf16x8*)&Ah[cur][off];
            al[mf] = *(const bf16x8*)&Al[cur][off];
        }
        const short* wb = Wmhi + ((size_t)(s * 4 + sub) * 256 + wn * 128) * 8;
        const short* wl = Wmlo + ((size_t)(s * 4 + sub) * 256 + wn * 128) * 8;
        #pragma unroll
        for (int nf = 0; nf < 8; ++nf) {
            bf16x8 bh = *(const bf16x8*)(wb + (nf * 16 + l15) * 8);
            bf16x8 bl = *(const bf16x8*)(wl + (nf * 16 + l15) * 8);
            #pragma unroll
            for (int mf = 0; mf < 2; ++mf) {
                acc[mf][nf] = __builtin_amdgcn_mfma_f32_16x16x32_bf16(ah[mf], bh, acc[mf][nf], 0, 0, 0);
                acc[mf][nf] = __builtin_amdgcn_mfma_f32_16x16x32_bf16(ah[mf], bl, acc[mf][nf], 0, 0, 0);
                acc[mf][nf] = __builtin_amdgcn_mfma_f32_16x16x32_bf16(al[mf], bh, acc[mf][nf], 0, 0, 0);
            }
        }
        cur ^= 1;
    }

    #pragma unroll
    for (int mf = 0; mf < 2; ++mf) {
        int mrow = m0 + wm * 32 + mf * 16 + sub * 4;
        #pragma unroll
        for (int nf = 0; nf < 8; ++nf) {
            int n = wn * 128 + nf * 16 + l15;
            #pragma unroll
            for (int rg = 0; rg < 4; ++rg)
                atomicAdd(&accum[(size_t)(mrow + rg) * D2 + n], acc[mf][nf][rg]);
        }
    }
}

// =====================================================================
// K4b: accum + bias + BN + positional encoding -> a_pe
// =====================================================================
__global__ __launch_bounds__(256)
void k_map2fin(const float* __restrict__ accum, const float* __restrict__ mb,
               const float* __restrict__ bn, float* __restrict__ out)
{
    const int row = blockIdx.x;
    const int n   = threadIdx.x;
    float acc = accum[(size_t)row * D2 + n];

    float s    = bn[n] * rsqrtf(bn[768 + n] + 1e-5f);
    float beta = bn[256 + n];
    float mu   = bn[512 + n];
    float bias = mb[n];
    int   jj   = n >> 1;
    float freq = expf((float)(2 * jj) * (-4.605170185988092f / 256.f)); // -ln(100)/256
    int   t    = (row >> 2) % 6;
    float ang  = (float)t * freq;
    float pe   = (n & 1) ? cosf(ang) : sinf(ang);
    out[(size_t)row * D2 + n] = (acc + bias - mu) * s + beta + pe;
}

// =====================================================================
// K5: MPNN block (win=2). one block per graph, block 256
// =====================================================================
__global__ __launch_bounds__(256)
void k_mpnn(const float* __restrict__ a_pe, const float* __restrict__ gw,
            const float* __restrict__ gb, const float* __restrict__ bnA,
            const float* __restrict__ tw, const float* __restrict__ tb_,
            const float* __restrict__ bnM, float* __restrict__ feats,
            int nw, int stride, int base)
{
    const int g  = blockIdx.x;
    const int b  = g / nw, wi = g % nw;
    const int tid = threadIdx.x;

    __shared__ float Xc[8][256];
    __shared__ float Xb[8][256];
    __shared__ float Fs[8][256];
    __shared__ float Adj[8][8];
    __shared__ float hsm[8][128];

    for (int e = tid; e < 2048; e += 256) {
        int nn = e >> 8, d = e & 255;
        int tt = nn >> 2, sn = nn & 3;
        float v = a_pe[(((size_t)(b * 6) + (wi * stride + tt)) * 4 + sn) * D2 + d];
        Xc[nn][d] = v;
        float s = bnA[d] * rsqrtf(bnA[768 + d] + 1e-5f);
        Xb[nn][d] = (v - bnA[512 + d]) * s + bnA[256 + d];
    }
    __syncthreads();

    {   // f = Xc @ gw + gb
        const int d = tid;
        #pragma unroll
        for (int nn = 0; nn < 8; ++nn) {
            float acc = gb[d];
            for (int k = 0; k < 256; ++k) acc += Xc[nn][k] * gw[(size_t)k * D2 + d];
            Fs[nn][d] = acc;
        }
    }
    __syncthreads();

    if (tid < 64) {
        int nn = tid >> 3, m = tid & 7;
        float s = 0.f;
        for (int d = 0; d < 256; ++d) s += Fs[nn][d] * Fs[m][d];
        if (nn == m) s -= 1e8f;
        s = (s > 0.f) ? s : 0.01f * s;
        Adj[nn][m] = s;
    }
    __syncthreads();

    if (tid < 8) {
        int nn = tid;
        float mx = -1e30f;
        for (int m = 0; m < 8; ++m) mx = fmaxf(mx, Adj[nn][m]);
        float ex[8]; float sum = 0.f;
        for (int m = 0; m < 8; ++m) { ex[m] = expf(Adj[nn][m] - mx); sum += ex[m]; }
        float inv = 1.f / sum;
        for (int m = 0; m < 8; ++m) {
            float v = ex[m] * inv + ((nn == m) ? 1.f : 0.f);
            v *= ((nn >> 2) == (m >> 2)) ? 1.f : 0.7f;
            Adj[nn][m] = v;
        }
    }
    __syncthreads();

    {   // hmid = Adj @ Xb
        const int d = tid;
        float hm[8];
        #pragma unroll
        for (int nn = 0; nn < 8; ++nn) {
            float a = 0.f;
            #pragma unroll
            for (int m = 0; m < 8; ++m) a += Adj[nn][m] * Xb[m][d];
            hm[nn] = a;
        }
        #pragma unroll
        for (int nn = 0; nn < 8; ++nn) Fs[nn][d] = hm[nn];
    }
    __syncthreads();

    {   // h = leaky(BN(hmid @ tw + tb))
        const int o = tid & 127, half = tid >> 7;
        float ms  = bnM[o] * rsqrtf(bnM[384 + o] + 1e-5f);
        float mbe = bnM[128 + o], mmu = bnM[256 + o];
        #pragma unroll
        for (int q = 0; q < 4; ++q) {
            int nn = half + 2 * q;
            float acc = tb_[o];
            for (int d = 0; d < 256; ++d) acc += Fs[nn][d] * tw[(size_t)d * HIDN + o];
            float y = (acc - mmu) * ms + mbe;
            hsm[nn][o] = (y > 0.f) ? y : 0.01f * y;
        }
    }
    __syncthreads();

    for (int e = tid; e < 512; e += 256) {
        int sn = e >> 7, o = e & 127;
        feats[(size_t)b * 4096 + base + (wi * 4 + sn) * HIDN + o] =
            0.5f * (hsm[sn][o] + hsm[4 + sn][o]);
    }
}

// =====================================================================
// K6a: fc1 split-K. grid = 16 k-chunks x 8 n-chunks = 128 blocks.
// =====================================================================
__global__ __launch_bounds__(256)
void k_fc1(const float* __restrict__ feats, const float* __restrict__ w1f,
           float* __restrict__ partfc)
{
    const int kc = blockIdx.x >> 3;
    const int nc = blockIdx.x & 7;
    const int tid = threadIdx.x;

    __shared__ float fst[32 * 257];

    for (int idx = tid; idx < 32 * 256; idx += 256) {
        int r = idx >> 8, k = idx & 255;
        fst[r * 257 + k] = feats[(size_t)r * 4096 + kc * 256 + k];
    }
    __syncthreads();

    const int c  = tid & 31;
    const int rg = tid >> 5;
    const float* wp = w1f + (size_t)(kc * 256) * 256 + nc * 32 + c;

    float acc[4] = {0.f, 0.f, 0.f, 0.f};
    for (int k = 0; k < 256; ++k) {
        float wv = wp[(size_t)k * 256];
        #pragma unroll
        for (int j = 0; j < 4; ++j)
            acc[j] += fst[(rg * 4 + j) * 257 + k] * wv;
    }
    #pragma unroll
    for (int j = 0; j < 4; ++j)
        partfc[((size_t)kc * 32 + rg * 4 + j) * 256 + nc * 32 + c] = acc[j];
}

// =====================================================================
// K6b: reduce fc1 partials + relu, then fc2/fc3/fc4. one block per row.
// =====================================================================
__global__ __launch_bounds__(256)
void k_fc_rest(const float* __restrict__ partfc,
               const float* __restrict__ b1f,
               const float* __restrict__ w2f, const float* __restrict__ b2f,
               const float* __restrict__ w3f, const float* __restrict__ b3f,
               const float* __restrict__ w4f, const float* __restrict__ b4f,
               float* __restrict__ out)
{
    const int b = blockIdx.x;
    const int n = threadIdx.x;
    __shared__ float h1[256], h2[256], h3[128];

    {
        float acc = b1f[n];
        #pragma unroll
        for (int kc = 0; kc < 16; ++kc)
            acc += partfc[((size_t)kc * 32 + b) * 256 + n];
        h1[n] = fmaxf(acc, 0.f);
    }
    __syncthreads();
    {
        float acc = b2f[n];
        for (int k = 0; k < 256; ++k) acc += h1[k] * w2f[(size_t)k * 256 + n];
        h2[n] = fmaxf(acc, 0.f);
    }
    __syncthreads();
    if (n < 128) {
        float acc = b3f[n];
        for (int k = 0; k < 256; ++k) acc += h2[k] * w3f[(size_t)k * 128 + n];
        h3[n] = fmaxf(acc, 0.f);
    }
    __syncthreads();
    if (n < 5) {
        float acc = b4f[n];
        for (int k = 0; k < 128; ++k) acc += h3[k] * w4f[(size_t)k * 5 + n];
        out[b * 5 + n] = acc;
    }
}

// =====================================================================
extern "C" void kernel_launch(void* const* d_in, const int* in_sizes, int n_in,
                              void* d_out, int out_size, void* d_ws, size_t ws_size,
                              hipStream_t stream)
{
    const float* X      = (const float*)d_in[0];
    const float* w1     = (const float*)d_in[1];
    const float* bn1    = (const float*)d_in[2];
    const float* w2     = (const float*)d_in[3];
    const float* bn2    = (const float*)d_in[4];
    const float* w3     = (const float*)d_in[5];
    const float* bn3    = (const float*)d_in[6];
    const float* map2w  = (const float*)d_in[7];
    const float* map2b  = (const float*)d_in[8];
    const float* bnm2   = (const float*)d_in[9];
    const float* g1w    = (const float*)d_in[10];
    const float* g1b    = (const float*)d_in[11];
    const float* bnA1   = (const float*)d_in[12];
    const float* th1w   = (const float*)d_in[13];
    const float* th1b   = (const float*)d_in[14];
    const float* bnM1   = (const float*)d_in[15];
    const float* g2w    = (const float*)d_in[16];
    const float* g2b    = (const float*)d_in[17];
    const float* bnA2   = (const float*)d_in[18];
    const float* th2w   = (const float*)d_in[19];
    const float* th2b   = (const float*)d_in[20];
    const float* bnM2   = (const float*)d_in[21];
    const float* fc1w   = (const float*)d_in[22];
    const float* fc1b   = (const float*)d_in[23];
    const float* fc2w   = (const float*)d_in[24];
    const float* fc2b   = (const float*)d_in[25];
    const float* fc3w   = (const float*)d_in[26];
    const float* fc3b   = (const float*)d_in[27];
    const float* fc4w   = (const float*)d_in[28];
    const float* fc4b   = (const float*)d_in[29];
    float* out = (float*)d_out;

    // ---- workspace layout (all region sizes 16B-multiples) ----
    float* ws = (float*)d_ws;
    float* pool2t = ws;                                   // 96*377*128 = 4,632,576 f
    short* p3hi   = (short*)(ws + 4632576);               // 768*24448 = 18,776,064 s
    short* p3lo   = p3hi + 18776064;
    float* a_pe   = (float*)(p3lo + 18776064);            // 196,608 f
    float* feats  = a_pe + 196608;                        // 131,072 f
    short* Wt2hi  = (short*)(feats + 131072);             // 24,576 s
    short* Wt2lo  = Wt2hi + 24576;
    short* Wt3hi  = Wt2lo + 24576;                        // 49,152 s
    short* Wt3lo  = Wt3hi + 49152;
    float* partfc = (float*)(Wt3lo + 49152);              // 131,072 f
    short* Wmhi   = (short*)(partfc + 131072);            // 764*4*256*8 = 6,258,688 s
    short* Wmlo   = Wmhi + 6258688;
    float* accum  = ws;                                   // aliases pool2t (free then)

    k_wprep<64, 2><<<96, 256, 0, stream>>>(w2, Wt2hi, Wt2lo);
    k_wprep<128, 4><<<192, 256, 0, stream>>>(w3, Wt3hi, Wt3lo);
    k_wmprep<<<KSTEPS * 4, 256, 0, stream>>>(map2w, Wmhi, Wmlo);

    for (int boff = 0; boff < 768; boff += 96) {
        k_conv2_mfma<<<96 * 6, 256, 0, stream>>>(X, w1, bn1, Wt2hi, Wt2lo, bn2,
                                                 pool2t, boff);
        k_conv3_mfma<<<96 * 3, 256, 0, stream>>>(pool2t, Wt3hi, Wt3lo, bn3,
                                                 p3hi, p3lo, boff);
    }
    k_zero<<<768, 256, 0, stream>>>(accum, 196608);
    k_map2_mfma<<<384, 256, 0, stream>>>(p3hi, p3lo, Wmhi, Wmlo, accum);
    k_map2fin<<<768, 256, 0, stream>>>(accum, map2b, bnm2, a_pe);
    k_mpnn<<<160, 256, 0, stream>>>(a_pe, g1w, g1b, bnA1, th1w, th1b, bnM1,
                                    feats, 5, 1, 0);
    k_mpnn<<<96, 256, 0, stream>>>(a_pe, g2w, g2b, bnA2, th2w, th2b, bnM2,
                                   feats, 3, 2, 2560);
    k_fc1<<<128, 256, 0, stream>>>(feats, fc1w, partfc);
    k_fc_rest<<<32, 256, 0, stream>>>(partfc, fc1b, fc2w, fc2b, fc3w, fc3b,
                                      fc4w, fc4b, out);
}

// Round 8
// 678.998 us; speedup vs baseline: 1.0939x; 1.0939x over previous
//
#include <hip/hip_runtime.h>
#include <hip/hip_bf16.h>

// ---------------- constants ----------------
#define L1X   1500   // raw sequence length
#define L1P   751    // pool1 length (t in [0,750])
#define C1    64
#define L2P   377    // pool2 length
#define C2    128
#define L3P   191    // pool3 length
#define C3    128
#define FEATK 24448  // L3P*C3 (stored [i][c] -> k = i*128 + c)
#define D2    256
#define HIDN  128
#define KSTEPS 764   // FEATK / 32
#define CHUNK 192    // conv pipeline rows per iteration

typedef __attribute__((ext_vector_type(8))) short bf16x8;
typedef __attribute__((ext_vector_type(4))) float f32x4;

__device__ __forceinline__ short f2bf(float x) {
    union { float f; unsigned u; } v; v.f = x;
    unsigned r = (v.u + 0x7FFFu + ((v.u >> 16) & 1u)) >> 16;
    return (short)r;
}
__device__ __forceinline__ float bf2f(short s) {
    union { float f; unsigned u; } v; v.u = ((unsigned)(unsigned short)s) << 16;
    return v.f;
}

// =====================================================================
// Conv weight prep: w[OC=128][IC][3] fp32 -> Wt[tap][kb][sub][c][8] bf16 hi/lo
// =====================================================================
template<int IC, int KB>
__global__ __launch_bounds__(256)
void k_wprep(const float* __restrict__ w, short* __restrict__ WtHi,
             short* __restrict__ WtLo)
{
    int idx = blockIdx.x * 256 + threadIdx.x;
    if (idx >= 3 * KB * 4 * 128 * 8) return;
    int i    = idx & 7;
    int rest = idx >> 3;
    int c    = rest & 127; rest >>= 7;
    int sub  = rest & 3;   rest >>= 2;
    int kb   = rest % KB;
    int tap  = rest / KB;
    int ic   = kb * 32 + sub * 8 + i;
    float x  = w[(c * IC + ic) * 3 + tap];
    short h  = f2bf(x);
    WtHi[idx] = h;
    WtLo[idx] = f2bf(x - bf2f(h));
}

// =====================================================================
// map2 weight prep: W[f=c*191+ip][n] fp32 -> Wm[ks][sub][n][i] bf16 hi/lo
// =====================================================================
__global__ __launch_bounds__(256)
void k_wmprep(const float* __restrict__ W, short* __restrict__ Wmhi,
              short* __restrict__ Wmlo)
{
    const int ks  = blockIdx.x >> 2;
    const int sub = blockIdx.x & 3;
    const int n   = threadIdx.x;
    const int kbase = ks * 32 + sub * 8;
    bf16x8 vh, vl;
    #pragma unroll
    for (int i = 0; i < 8; ++i) {
        int k = kbase + i;
        int c = k & 127, ip = k >> 7;
        float x = W[(size_t)(c * 191 + ip) * D2 + n];
        short h = f2bf(x);
        vh[i] = h;
        vl[i] = f2bf(x - bf2f(h));
    }
    size_t off = ((size_t)(ks * 4 + sub) * 256 + n) * 8;
    *(bf16x8*)(Wmhi + off) = vh;
    *(bf16x8*)(Wmlo + off) = vl;
}

// =====================================================================
__global__ __launch_bounds__(256)
void k_zero(float* __restrict__ p, int n)
{
    int i = blockIdx.x * 256 + threadIdx.x;
    if (i < n) p[i] = 0.f;
}

// =====================================================================
// Shared MFMA conv core. HL=false: fp32 [i][c] out. HL=true: bf16 hi/lo planes.
// =====================================================================
template<int IC, int KB, int CONVLEN, int POOLLEN, bool HL>
__device__ __forceinline__
void conv_mfma_core(const short* __restrict__ WtHi, const short* __restrict__ WtLo,
                    const short* lhi, const short* llo,
                    const float* sc, const float* bc,
                    float* __restrict__ outp, short* __restrict__ ohi,
                    short* __restrict__ olo, int P0)
{
    const int lane = threadIdx.x & 63;
    const int wave = threadIdx.x >> 6;
    const int l15  = lane & 15;
    const int sub  = lane >> 4;

    f32x4 acc[2][8];
    #pragma unroll
    for (int mf = 0; mf < 2; ++mf)
        #pragma unroll
        for (int nf = 0; nf < 8; ++nf)
            acc[mf][nf] = (f32x4){0.f, 0.f, 0.f, 0.f};

    #pragma unroll
    for (int tap = 0; tap < 3; ++tap) {
        #pragma unroll
        for (int kb = 0; kb < KB; ++kb) {
            bf16x8 ah[2], al[2];
            #pragma unroll
            for (int mf = 0; mf < 2; ++mf) {
                int r = wave * 32 + mf * 16 + l15 + tap;
                int chunk = (kb * 4 + sub) ^ (r & 7);
                int off = r * IC + chunk * 8;
                ah[mf] = *(const bf16x8*)(lhi + off);
                al[mf] = *(const bf16x8*)(llo + off);
            }
            const short* wbh = WtHi + (size_t)(((tap * KB + kb) * 4 + sub) * 128) * 8;
            const short* wbl = WtLo + (size_t)(((tap * KB + kb) * 4 + sub) * 128) * 8;
            #pragma unroll
            for (int nf = 0; nf < 8; ++nf) {
                bf16x8 bh = *(const bf16x8*)(wbh + (nf * 16 + l15) * 8);
                bf16x8 bl = *(const bf16x8*)(wbl + (nf * 16 + l15) * 8);
                #pragma unroll
                for (int mf = 0; mf < 2; ++mf) {
                    acc[mf][nf] = __builtin_amdgcn_mfma_f32_16x16x32_bf16(ah[mf], bh, acc[mf][nf], 0, 0, 0);
                    acc[mf][nf] = __builtin_amdgcn_mfma_f32_16x16x32_bf16(ah[mf], bl, acc[mf][nf], 0, 0, 0);
                    acc[mf][nf] = __builtin_amdgcn_mfma_f32_16x16x32_bf16(al[mf], bh, acc[mf][nf], 0, 0, 0);
                }
            }
        }
    }

    #pragma unroll
    for (int mf = 0; mf < 2; ++mf) {
        int mbase = wave * 32 + mf * 16 + sub * 4;
        #pragma unroll
        for (int nf = 0; nf < 8; ++nf) {
            int c = nf * 16 + l15;
            float s = sc[c], bb = bc[c];
            float v[4];
            #pragma unroll
            for (int rg = 0; rg < 4; ++rg) {
                int p = P0 + mbase + rg;
                float x = fmaxf(acc[mf][nf][rg] * s + bb, 0.f);
                v[rg] = (p >= 0 && p < CONVLEN) ? x : 0.f;
            }
            int i0 = (P0 + mbase + 1) >> 1;    // pooled index (P0 odd)
            float u0 = fmaxf(v[0], v[1]);
            float u1 = fmaxf(v[2], v[3]);
            if constexpr (HL) {
                if (i0 < POOLLEN) {
                    short h = f2bf(u0);
                    ohi[(size_t)i0 * 128 + c] = h;
                    olo[(size_t)i0 * 128 + c] = f2bf(u0 - bf2f(h));
                }
                if (i0 + 1 < POOLLEN) {
                    short h = f2bf(u1);
                    ohi[(size_t)(i0 + 1) * 128 + c] = h;
                    olo[(size_t)(i0 + 1) * 128 + c] = f2bf(u1 - bf2f(h));
                }
            } else {
                if (i0 < POOLLEN)     outp[(size_t)i0 * 128 + c] = u0;
                if (i0 + 1 < POOLLEN) outp[(size_t)(i0 + 1) * 128 + c] = u1;
            }
        }
    }
}

// =====================================================================
// conv2 (fused conv1+bn1+relu+pool1 recompute prologue) -> MFMA
// output: pool2 bf16 hi/lo planes [local row][i*128+c]
// =====================================================================
__global__ __launch_bounds__(256)
void k_conv2_mfma(const float* __restrict__ X, const float* __restrict__ w1,
                  const float* __restrict__ bn1,
                  const short* __restrict__ Wt2hi, const short* __restrict__ Wt2lo,
                  const float* __restrict__ bn2, short* __restrict__ p2hi,
                  short* __restrict__ p2lo, int b_off)
{
    const int blk = blockIdx.x;
    const int bl  = blk / 6, t = blk % 6;
    const int b   = b_off + bl;
    const int P0  = 128 * t - 1;
    const int T0  = 128 * t - 3;
    const int X0  = 256 * t - 8;

    __shared__ __align__(16) float xw[264];
    __shared__ __align__(16) short t1h[130 * 64];
    __shared__ __align__(16) short t1l[130 * 64];
    __shared__ float sb1s[64], sb1b[64], sc2[128], bc2[128];

    const int tid = threadIdx.x;
    for (int g = tid; g < 262; g += 256) {
        int xi = X0 + g;
        xw[g] = (xi >= 0 && xi < L1X) ? X[(size_t)b * L1X + xi] : 0.f;
    }
    if (tid < 64) {
        float s = bn1[tid] * rsqrtf(bn1[192 + tid] + 1e-5f);
        sb1s[tid] = s;
        sb1b[tid] = bn1[64 + tid] - bn1[128 + tid] * s;
    }
    if (tid < 128) {
        float s = bn2[tid] * rsqrtf(bn2[384 + tid] + 1e-5f);
        sc2[tid] = s;
        bc2[tid] = bn2[128 + tid] - bn2[256 + tid] * s;
    }
    __syncthreads();

    for (int idx = tid; idx < 130 * 64; idx += 256) {
        int r = idx >> 6, c = idx & 63;
        int tt = T0 + r;
        float val = 0.f;
        if (tt >= 0 && tt <= 750) {
            float wk0 = w1[c * 3], wk1 = w1[c * 3 + 1], wk2 = w1[c * 3 + 2];
            float s = sb1s[c], bias = sb1b[c];
            float v0 = 0.f, v1 = 0.f;
            int li = 2 * r;
            if (tt >= 1)
                v0 = fmaxf((wk0 * xw[li] + wk1 * xw[li + 1] + wk2 * xw[li + 2]) * s + bias, 0.f);
            if (tt <= 749)
                v1 = fmaxf((wk0 * xw[li + 1] + wk1 * xw[li + 2] + wk2 * xw[li + 3]) * s + bias, 0.f);
            val = fmaxf(v0, v1);
        }
        short h = f2bf(val);
        int chunk = (c >> 3) ^ (r & 7);
        int off = r * 64 + chunk * 8 + (c & 7);
        t1h[off] = h;
        t1l[off] = f2bf(val - bf2f(h));
    }
    __syncthreads();

    conv_mfma_core<64, 2, 753, 377, true>(Wt2hi, Wt2lo, t1h, t1l, sc2, bc2,
                                          nullptr,
                                          p2hi + (size_t)bl * L2P * 128,
                                          p2lo + (size_t)bl * L2P * 128, P0);
}

// =====================================================================
// conv3 MFMA. Input: pool2 bf16 hi/lo planes (pure copy staging).
// Output: pool3 bf16 hi/lo planes [row][i*128+c]
// =====================================================================
__global__ __launch_bounds__(256)
void k_conv3_mfma(const short* __restrict__ p2hi, const short* __restrict__ p2lo,
                  const short* __restrict__ Wt3hi, const short* __restrict__ Wt3lo,
                  const float* __restrict__ bn3, short* __restrict__ p3hi,
                  short* __restrict__ p3lo, int b_off)
{
    const int blk = blockIdx.x;
    const int bl  = blk / 3, t = blk % 3;
    const int b   = b_off + bl;
    const int P0  = 128 * t - 1;
    const int I0  = 128 * t - 4;

    __shared__ __align__(16) short t2h[130 * 128];
    __shared__ __align__(16) short t2l[130 * 128];
    __shared__ float sc3[128], bc3[128];

    const int tid = threadIdx.x;
    if (tid < 128) {
        float s = bn3[tid] * rsqrtf(bn3[384 + tid] + 1e-5f);
        sc3[tid] = s;
        bc3[tid] = bn3[128 + tid] - bn3[256 + tid] * s;
    }

    const short* s2h = p2hi + (size_t)bl * L2P * 128;
    const short* s2l = p2lo + (size_t)bl * L2P * 128;
    for (int idx = tid; idx < 130 * 32; idx += 256) {
        int r = idx >> 5, q = idx & 31;
        int pr = I0 + r;
        short4 vh = make_short4(0, 0, 0, 0), vl = make_short4(0, 0, 0, 0);
        if (pr >= 0 && pr < L2P) {
            vh = *(const short4*)(s2h + (size_t)pr * 128 + q * 4);
            vl = *(const short4*)(s2l + (size_t)pr * 128 + q * 4);
        }
        int chunk = (q >> 1) ^ (r & 7);
        int off = r * 128 + chunk * 8 + (q & 1) * 4;
        *(short4*)(t2h + off) = vh;
        *(short4*)(t2l + off) = vl;
    }
    __syncthreads();

    conv_mfma_core<128, 4, 381, 191, true>(Wt3hi, Wt3lo, t2h, t2l, sc3, bc3,
                                           nullptr,
                                           p3hi + (size_t)b * FEATK,
                                           p3lo + (size_t)b * FEATK, P0);
}

// =====================================================================
// map2 MFMA GEMM: accum += A[768,24448] @ W[24448,256], split-bf16 3-pass.
// grid 576: kt = bid % 48 (same kt -> same XCD: 48 % 8 == 0), mt = bid / 48.
// 16 k-steps per kt (last 12). 8 accum copies (kt&7) cut atomic contention.
// =====================================================================
__global__ __launch_bounds__(256)
void k_map2_mfma(const short* __restrict__ Ahi, const short* __restrict__ Alo,
                 const short* __restrict__ Wmhi, const short* __restrict__ Wmlo,
                 float* __restrict__ accum)
{
    const int kt   = blockIdx.x % 48;
    const int mt   = blockIdx.x / 48;
    const int tid  = threadIdx.x;
    const int lane = tid & 63, wave = tid >> 6;
    const int l15  = lane & 15, sub = lane >> 4;
    const int wm   = wave >> 1, wn = wave & 1;
    const int m0   = mt * 64;

    const int s0 = kt * 16;
    const int s1 = (s0 + 16 < KSTEPS) ? s0 + 16 : KSTEPS;

    __shared__ __align__(16) short Ah[2][64 * 40];
    __shared__ __align__(16) short Al[2][64 * 40];

    const int r  = tid >> 2;
    const int kb = tid & 3;
    const size_t abase = (size_t)(m0 + r) * FEATK + kb * 8;
    const int    lbase = r * 40 + kb * 8;

    f32x4 acc[2][8];
    #pragma unroll
    for (int mf = 0; mf < 2; ++mf)
        #pragma unroll
        for (int nf = 0; nf < 8; ++nf)
            acc[mf][nf] = (f32x4){0.f, 0.f, 0.f, 0.f};

    *(bf16x8*)&Ah[0][lbase] = *(const bf16x8*)(Ahi + abase + (size_t)s0 * 32);
    *(bf16x8*)&Al[0][lbase] = *(const bf16x8*)(Alo + abase + (size_t)s0 * 32);

    int cur = 0;
    for (int s = s0; s < s1; ++s) {
        __syncthreads();
        if (s + 1 < s1) {
            *(bf16x8*)&Ah[cur ^ 1][lbase] = *(const bf16x8*)(Ahi + abase + (size_t)(s + 1) * 32);
            *(bf16x8*)&Al[cur ^ 1][lbase] = *(const bf16x8*)(Alo + abase + (size_t)(s + 1) * 32);
        }
        bf16x8 ah[2], al[2];
        #pragma unroll
        for (int mf = 0; mf < 2; ++mf) {
            int off = (wm * 32 + mf * 16 + l15) * 40 + sub * 8;
            ah[mf] = *(const bf16x8*)&Ah[cur][off];
            al[mf] = *(const bf16x8*)&Al[cur][off];
        }
        const short* wb = Wmhi + ((size_t)(s * 4 + sub) * 256 + wn * 128) * 8;
        const short* wl = Wmlo + ((size_t)(s * 4 + sub) * 256 + wn * 128) * 8;
        #pragma unroll
        for (int nf = 0; nf < 8; ++nf) {
            bf16x8 bh = *(const bf16x8*)(wb + (nf * 16 + l15) * 8);
            bf16x8 bl = *(const bf16x8*)(wl + (nf * 16 + l15) * 8);
            #pragma unroll
            for (int mf = 0; mf < 2; ++mf) {
                acc[mf][nf] = __builtin_amdgcn_mfma_f32_16x16x32_bf16(ah[mf], bh, acc[mf][nf], 0, 0, 0);
                acc[mf][nf] = __builtin_amdgcn_mfma_f32_16x16x32_bf16(ah[mf], bl, acc[mf][nf], 0, 0, 0);
                acc[mf][nf] = __builtin_amdgcn_mfma_f32_16x16x32_bf16(al[mf], bh, acc[mf][nf], 0, 0, 0);
            }
        }
        cur ^= 1;
    }

    float* acct = accum + (size_t)(kt & 7) * 196608;
    #pragma unroll
    for (int mf = 0; mf < 2; ++mf) {
        int mrow = m0 + wm * 32 + mf * 16 + sub * 4;
        #pragma unroll
        for (int nf = 0; nf < 8; ++nf) {
            int n = wn * 128 + nf * 16 + l15;
            #pragma unroll
            for (int rg = 0; rg < 4; ++rg)
                atomicAdd(&acct[(size_t)(mrow + rg) * D2 + n], acc[mf][nf][rg]);
        }
    }
}

// =====================================================================
// K4b: reduce 8 accum copies + bias + BN + positional encoding -> a_pe
// =====================================================================
__global__ __launch_bounds__(256)
void k_map2fin(const float* __restrict__ accum, const float* __restrict__ mb,
               const float* __restrict__ bn, float* __restrict__ out)
{
    const int row = blockIdx.x;
    const int n   = threadIdx.x;
    float acc = 0.f;
    #pragma unroll
    for (int c = 0; c < 8; ++c)
        acc += accum[(size_t)c * 196608 + (size_t)row * D2 + n];

    float s    = bn[n] * rsqrtf(bn[768 + n] + 1e-5f);
    float beta = bn[256 + n];
    float mu   = bn[512 + n];
    float bias = mb[n];
    int   jj   = n >> 1;
    float freq = expf((float)(2 * jj) * (-4.605170185988092f / 256.f)); // -ln(100)/256
    int   t    = (row >> 2) % 6;
    float ang  = (float)t * freq;
    float pe   = (n & 1) ? cosf(ang) : sinf(ang);
    out[(size_t)row * D2 + n] = (acc + bias - mu) * s + beta + pe;
}

// =====================================================================
// K5: MPNN block (win=2). one block per graph, block 256
// =====================================================================
__global__ __launch_bounds__(256)
void k_mpnn(const float* __restrict__ a_pe, const float* __restrict__ gw,
            const float* __restrict__ gb, const float* __restrict__ bnA,
            const float* __restrict__ tw, const float* __restrict__ tb_,
            const float* __restrict__ bnM, float* __restrict__ feats,
            int nw, int stride, int base)
{
    const int g  = blockIdx.x;
    const int b  = g / nw, wi = g % nw;
    const int tid = threadIdx.x;

    __shared__ float Xc[8][256];
    __shared__ float Xb[8][256];
    __shared__ float Fs[8][256];
    __shared__ float Adj[8][8];
    __shared__ float hsm[8][128];

    for (int e = tid; e < 2048; e += 256) {
        int nn = e >> 8, d = e & 255;
        int tt = nn >> 2, sn = nn & 3;
        float v = a_pe[(((size_t)(b * 6) + (wi * stride + tt)) * 4 + sn) * D2 + d];
        Xc[nn][d] = v;
        float s = bnA[d] * rsqrtf(bnA[768 + d] + 1e-5f);
        Xb[nn][d] = (v - bnA[512 + d]) * s + bnA[256 + d];
    }
    __syncthreads();

    {   // f = Xc @ gw + gb
        const int d = tid;
        #pragma unroll
        for (int nn = 0; nn < 8; ++nn) {
            float acc = gb[d];
            for (int k = 0; k < 256; ++k) acc += Xc[nn][k] * gw[(size_t)k * D2 + d];
            Fs[nn][d] = acc;
        }
    }
    __syncthreads();

    if (tid < 64) {
        int nn = tid >> 3, m = tid & 7;
        float s = 0.f;
        for (int d = 0; d < 256; ++d) s += Fs[nn][d] * Fs[m][d];
        if (nn == m) s -= 1e8f;
        s = (s > 0.f) ? s : 0.01f * s;
        Adj[nn][m] = s;
    }
    __syncthreads();

    if (tid < 8) {
        int nn = tid;
        float mx = -1e30f;
        for (int m = 0; m < 8; ++m) mx = fmaxf(mx, Adj[nn][m]);
        float ex[8]; float sum = 0.f;
        for (int m = 0; m < 8; ++m) { ex[m] = expf(Adj[nn][m] - mx); sum += ex[m]; }
        float inv = 1.f / sum;
        for (int m = 0; m < 8; ++m) {
            float v = ex[m] * inv + ((nn == m) ? 1.f : 0.f);
            v *= ((nn >> 2) == (m >> 2)) ? 1.f : 0.7f;
            Adj[nn][m] = v;
        }
    }
    __syncthreads();

    {   // hmid = Adj @ Xb
        const int d = tid;
        float hm[8];
        #pragma unroll
        for (int nn = 0; nn < 8; ++nn) {
            float a = 0.f;
            #pragma unroll
            for (int m = 0; m < 8; ++m) a += Adj[nn][m] * Xb[m][d];
            hm[nn] = a;
        }
        #pragma unroll
        for (int nn = 0; nn < 8; ++nn) Fs[nn][d] = hm[nn];
    }
    __syncthreads();

    {   // h = leaky(BN(hmid @ tw + tb))
        const int o = tid & 127, half = tid >> 7;
        float ms  = bnM[o] * rsqrtf(bnM[384 + o] + 1e-5f);
        float mbe = bnM[128 + o], mmu = bnM[256 + o];
        #pragma unroll
        for (int q = 0; q < 4; ++q) {
            int nn = half + 2 * q;
            float acc = tb_[o];
            for (int d = 0; d < 256; ++d) acc += Fs[nn][d] * tw[(size_t)d * HIDN + o];
            float y = (acc - mmu) * ms + mbe;
            hsm[nn][o] = (y > 0.f) ? y : 0.01f * y;
        }
    }
    __syncthreads();

    for (int e = tid; e < 512; e += 256) {
        int sn = e >> 7, o = e & 127;
        feats[(size_t)b * 4096 + base + (wi * 4 + sn) * HIDN + o] =
            0.5f * (hsm[sn][o] + hsm[4 + sn][o]);
    }
}

// =====================================================================
// K6a: fc1 split-K. grid = 16 k-chunks x 8 n-chunks = 128 blocks.
// =====================================================================
__global__ __launch_bounds__(256)
void k_fc1(const float* __restrict__ feats, const float* __restrict__ w1f,
           float* __restrict__ partfc)
{
    const int kc = blockIdx.x >> 3;
    const int nc = blockIdx.x & 7;
    const int tid = threadIdx.x;

    __shared__ float fst[32 * 257];

    for (int idx = tid; idx < 32 * 256; idx += 256) {
        int r = idx >> 8, k = idx & 255;
        fst[r * 257 + k] = feats[(size_t)r * 4096 + kc * 256 + k];
    }
    __syncthreads();

    const int c  = tid & 31;
    const int rg = tid >> 5;
    const float* wp = w1f + (size_t)(kc * 256) * 256 + nc * 32 + c;

    float acc[4] = {0.f, 0.f, 0.f, 0.f};
    for (int k = 0; k < 256; ++k) {
        float wv = wp[(size_t)k * 256];
        #pragma unroll
        for (int j = 0; j < 4; ++j)
            acc[j] += fst[(rg * 4 + j) * 257 + k] * wv;
    }
    #pragma unroll
    for (int j = 0; j < 4; ++j)
        partfc[((size_t)kc * 32 + rg * 4 + j) * 256 + nc * 32 + c] = acc[j];
}

// =====================================================================
// K6b: reduce fc1 partials + relu, then fc2/fc3/fc4. one block per row.
// =====================================================================
__global__ __launch_bounds__(256)
void k_fc_rest(const float* __restrict__ partfc,
               const float* __restrict__ b1f,
               const float* __restrict__ w2f, const float* __restrict__ b2f,
               const float* __restrict__ w3f, const float* __restrict__ b3f,
               const float* __restrict__ w4f, const float* __restrict__ b4f,
               float* __restrict__ out)
{
    const int b = blockIdx.x;
    const int n = threadIdx.x;
    __shared__ float h1[256], h2[256], h3[128];

    {
        float acc = b1f[n];
        #pragma unroll
        for (int kc = 0; kc < 16; ++kc)
            acc += partfc[((size_t)kc * 32 + b) * 256 + n];
        h1[n] = fmaxf(acc, 0.f);
    }
    __syncthreads();
    {
        float acc = b2f[n];
        for (int k = 0; k < 256; ++k) acc += h1[k] * w2f[(size_t)k * 256 + n];
        h2[n] = fmaxf(acc, 0.f);
    }
    __syncthreads();
    if (n < 128) {
        float acc = b3f[n];
        for (int k = 0; k < 256; ++k) acc += h2[k] * w3f[(size_t)k * 128 + n];
        h3[n] = fmaxf(acc, 0.f);
    }
    __syncthreads();
    if (n < 5) {
        float acc = b4f[n];
        for (int k = 0; k < 128; ++k) acc += h3[k] * w4f[(size_t)k * 5 + n];
        out[b * 5 + n] = acc;
    }
}

// =====================================================================
extern "C" void kernel_launch(void* const* d_in, const int* in_sizes, int n_in,
                              void* d_out, int out_size, void* d_ws, size_t ws_size,
                              hipStream_t stream)
{
    const float* X      = (const float*)d_in[0];
    const float* w1     = (const float*)d_in[1];
    const float* bn1    = (const float*)d_in[2];
    const float* w2     = (const float*)d_in[3];
    const float* bn2    = (const float*)d_in[4];
    const float* w3     = (const float*)d_in[5];
    const float* bn3    = (const float*)d_in[6];
    const float* map2w  = (const float*)d_in[7];
    const float* map2b  = (const float*)d_in[8];
    const float* bnm2   = (const float*)d_in[9];
    const float* g1w    = (const float*)d_in[10];
    const float* g1b    = (const float*)d_in[11];
    const float* bnA1   = (const float*)d_in[12];
    const float* th1w   = (const float*)d_in[13];
    const float* th1b   = (const float*)d_in[14];
    const float* bnM1   = (const float*)d_in[15];
    const float* g2w    = (const float*)d_in[16];
    const float* g2b    = (const float*)d_in[17];
    const float* bnA2   = (const float*)d_in[18];
    const float* th2w   = (const float*)d_in[19];
    const float* th2b   = (const float*)d_in[20];
    const float* bnM2   = (const float*)d_in[21];
    const float* fc1w   = (const float*)d_in[22];
    const float* fc1b   = (const float*)d_in[23];
    const float* fc2w   = (const float*)d_in[24];
    const float* fc2b   = (const float*)d_in[25];
    const float* fc3w   = (const float*)d_in[26];
    const float* fc3b   = (const float*)d_in[27];
    const float* fc4w   = (const float*)d_in[28];
    const float* fc4b   = (const float*)d_in[29];
    float* out = (float*)d_out;

    // ---- workspace layout (region A aliased across phases) ----
    // conv phase:  region A = p2hi/p2lo (192-row chunk, bf16 hi/lo)
    // map2 phase:  region A = Wmhi/Wmlo + 8 accum copies
    float* ws = (float*)d_ws;
    const size_t SZ_P2 = (size_t)CHUNK * L2P * 128;       // 9,264,384 shorts/plane
    short* p2hi  = (short*)ws;
    short* p2lo  = p2hi + SZ_P2;
    short* Wmhi  = (short*)ws;                            // map2 phase (aliases p2)
    short* Wmlo  = Wmhi + 6258688;
    float* accum = (float*)(Wmlo + 6258688);              // 8 * 196608 floats
    // region A total: max(2*9,264,384 shorts, 12,517,376 shorts + 1,572,864 f) = 9,264,384 floats
    float* after  = ws + 9264384;
    short* p3hi   = (short*)after;                        // 18,776,064 shorts
    short* p3lo   = p3hi + 18776064;
    float* a_pe   = (float*)(p3lo + 18776064);            // 196,608 f
    float* feats  = a_pe + 196608;                        // 131,072 f
    short* Wt2hi  = (short*)(feats + 131072);             // 24,576 s
    short* Wt2lo  = Wt2hi + 24576;
    short* Wt3hi  = Wt2lo + 24576;                        // 49,152 s
    short* Wt3lo  = Wt3hi + 49152;
    float* partfc = (float*)(Wt3lo + 49152);              // 131,072 f

    k_wprep<64, 2><<<96, 256, 0, stream>>>(w2, Wt2hi, Wt2lo);
    k_wprep<128, 4><<<192, 256, 0, stream>>>(w3, Wt3hi, Wt3lo);

    for (int boff = 0; boff < 768; boff += CHUNK) {
        k_conv2_mfma<<<CHUNK * 6, 256, 0, stream>>>(X, w1, bn1, Wt2hi, Wt2lo, bn2,
                                                    p2hi, p2lo, boff);
        k_conv3_mfma<<<CHUNK * 3, 256, 0, stream>>>(p2hi, p2lo, Wt3hi, Wt3lo, bn3,
                                                    p3hi, p3lo, boff);
    }
    // map2 phase (region A now holds Wm + accum)
    k_wmprep<<<KSTEPS * 4, 256, 0, stream>>>(map2w, Wmhi, Wmlo);
    k_zero<<<(8 * 196608 + 255) / 256, 256, 0, stream>>>(accum, 8 * 196608);
    k_map2_mfma<<<576, 256, 0, stream>>>(p3hi, p3lo, Wmhi, Wmlo, accum);
    k_map2fin<<<768, 256, 0, stream>>>(accum, map2b, bnm2, a_pe);
    k_mpnn<<<160, 256, 0, stream>>>(a_pe, g1w, g1b, bnA1, th1w, th1b, bnM1,
                                    feats, 5, 1, 0);
    k_mpnn<<<96, 256, 0, stream>>>(a_pe, g2w, g2b, bnA2, th2w, th2b, bnM2,
                                   feats, 3, 2, 2560);
    k_fc1<<<128, 256, 0, stream>>>(feats, fc1w, partfc);
    k_fc_rest<<<32, 256, 0, stream>>>(partfc, fc1b, fc2w, fc2b, fc3w, fc3b,
                                      fc4w, fc4b, out);
}